// Round 6
// baseline (387.868 us; speedup 1.0000x reference)
//
#include <hip/hip_runtime.h>
#include <math.h>

#define NB 8
#define NC 256
#define NHW 1024
#define NHEADS 8
#define HD 32

typedef _Float16 half_t;
typedef __attribute__((ext_vector_type(8))) _Float16 half8;
typedef __attribute__((ext_vector_type(2))) _Float16 half2v;
typedef __attribute__((ext_vector_type(4))) float floatx4;

#if __has_builtin(__builtin_amdgcn_exp2f)
#define EXP2(x) __builtin_amdgcn_exp2f(x)
#else
#define EXP2(x) __expf((x) * 0.6931471805599453f)
#endif

__device__ __forceinline__ half2v pk2(float a, float b) {
    union {
        __fp16 __attribute__((ext_vector_type(2))) r;
        half2v h;
    } u;
    u.r = __builtin_amdgcn_cvt_pkrtz(a, b);  // v_cvt_pkrtz_f16_f32
    return u.h;
}
__device__ __forceinline__ void st8h(half_t* p, half2v a, half2v b) {
    union { half2v h[2]; uint2 u; } t;
    t.h[0] = a; t.h[1] = b;
    *(uint2*)p = t.u;  // 8B store, p must be 8B-aligned
}

// ---- device-scope grid barrier: 16-way split arrival counters, relaxed polls ----
__device__ __forceinline__ void grid_barrier(unsigned* bar, unsigned nblk) {
    __syncthreads();  // drains vmcnt: all block stores are at least in local L2
    if (threadIdx.x == 0) {
        __threadfence();  // release: write back dirty L2 (cross-XCD visibility)
        __hip_atomic_fetch_add(&bar[blockIdx.x & 15], 1u,
                               __ATOMIC_RELAXED, __HIP_MEMORY_SCOPE_AGENT);
        for (;;) {
            unsigned tot = 0;
            #pragma unroll
            for (int i = 0; i < 16; i++)
                tot += __hip_atomic_load(&bar[i], __ATOMIC_RELAXED,
                                         __HIP_MEMORY_SCOPE_AGENT);
            if (tot >= nblk) break;
            __builtin_amdgcn_s_sleep(2);
        }
        __threadfence();  // acquire: invalidate caches
    }
    __syncthreads();
}

// ================= Kernel A: prep (weights + x transpose) -> barrier -> QKV =================
// Q -> Qt[bh][s][d] scaled by (1/sqrt(32))*log2(e); K -> Kt[bh][s][d]; V -> Vv[bh][d][s]
__device__ __forceinline__ void qkv_tile(int v,
    const half_t* __restrict__ xT, const half_t* __restrict__ Wh,
    const float* __restrict__ bq, const float* __restrict__ bk, const float* __restrict__ bv,
    half_t* __restrict__ Qt, half_t* __restrict__ Kt, half_t* __restrict__ Vv)
{
    int bx = v & 15, by = (v >> 4) & 3, bz = v >> 6;
    int b = bz & 7, pp = bz >> 3;  // wave-uniform
    const half_t* W    = Wh + (size_t)pp * NC * NC;
    const float*  bias = (pp == 0) ? bq : (pp == 1) ? bk : bv;

    int wv = threadIdx.x >> 6, lane = threadIdx.x & 63;
    int mm = lane & 15, q = lane >> 4;
    int o0 = by * 64 + wv * 16;
    int s0 = bx * 64;

    const half_t* xb = xT + (size_t)b * NHW * NC;
    floatx4 acc[4];
    #pragma unroll
    for (int nt = 0; nt < 4; nt++) acc[nt] = (floatx4){0.f, 0.f, 0.f, 0.f};

    #pragma unroll
    for (int k0 = 0; k0 < NC; k0 += 32) {
        half8 af = *(const half8*)&W[(size_t)(o0 + mm) * NC + k0 + q * 8];
        #pragma unroll
        for (int nt = 0; nt < 4; nt++) {
            half8 bf = *(const half8*)&xb[(size_t)(s0 + nt * 16 + mm) * NC + k0 + q * 8];
            acc[nt] = __builtin_amdgcn_mfma_f32_16x16x32_f16(af, bf, acc[nt], 0, 0, 0);
        }
    }

    int h  = o0 >> 5;
    int bh = b * NHEADS + h;
    int d0 = (o0 & 31) + q * 4;
    float bb[4];
    #pragma unroll
    for (int r = 0; r < 4; r++) bb[r] = bias[o0 + q * 4 + r];
    // 1/sqrt(32) * log2(e): softmax via exp2
    const float qs = 0.17677669529663687f * 1.4426950408889634f;

    #pragma unroll
    for (int nt = 0; nt < 4; nt++) {
        int s = s0 + nt * 16 + mm;
        float v0 = acc[nt][0] + bb[0], v1 = acc[nt][1] + bb[1];
        float v2 = acc[nt][2] + bb[2], v3 = acc[nt][3] + bb[3];
        if (pp == 0) { v0 *= qs; v1 *= qs; v2 *= qs; v3 *= qs; }
        if (pp < 2) {
            half_t* out = (pp == 0 ? Qt : Kt) + ((size_t)bh * NHW + s) * HD + d0;
            st8h(out, pk2(v0, v1), pk2(v2, v3));
        } else {
            Vv[((size_t)bh * HD + d0 + 0) * NHW + s] = (half_t)v0;
            Vv[((size_t)bh * HD + d0 + 1) * NHW + s] = (half_t)v1;
            Vv[((size_t)bh * HD + d0 + 2) * NHW + s] = (half_t)v2;
            Vv[((size_t)bh * HD + d0 + 3) * NHW + s] = (half_t)v3;
        }
    }
}

__global__ __launch_bounds__(256, 4) void mega_a(
    const float* __restrict__ Wq, const float* __restrict__ Wk,
    const float* __restrict__ Wv, const float* __restrict__ Wp,
    const float* __restrict__ x,
    const float* __restrict__ bq, const float* __restrict__ bk, const float* __restrict__ bv,
    half_t* __restrict__ Wh, half_t* __restrict__ xT,
    half_t* __restrict__ Qt, half_t* __restrict__ Kt, half_t* __restrict__ Vv,
    unsigned* bar)
{
    __shared__ half_t tile[64][66];
    int p = blockIdx.x;
    int t = threadIdx.x;

    if (p < 512) {
        // x transpose tile: [b][c][s] fp32 -> [b][s][c] f16
        int b = p >> 6;
        int i0 = ((p >> 4) & 3) * 64, s0 = (p & 15) * 64;
        const float* xb = x + ((size_t)b * NC + i0) * NHW + s0;
        int s4 = t & 15, il = t >> 4;
        #pragma unroll
        for (int r = 0; r < 4; r++) {
            int i = il + 16 * r;
            float4 vv = *(const float4*)&xb[i * NHW + s4 * 4];
            *(half2v*)&tile[i][s4 * 4]     = pk2(vv.x, vv.y);
            *(half2v*)&tile[i][s4 * 4 + 2] = pk2(vv.z, vv.w);
        }
        __syncthreads();
        int iv = t & 7, sl = t >> 3;
        half_t* ob = xT + ((size_t)b * NHW + s0) * NC + i0 + iv * 8;
        #pragma unroll
        for (int r = 0; r < 2; r++) {
            int s = sl + 32 * r;
            union { half_t h[8]; int4 v4; } pkd;
            #pragma unroll
            for (int u = 0; u < 8; u++) pkd.h[u] = tile[iv * 8 + u][s];
            *(int4*)&ob[(size_t)s * NC] = pkd.v4;
        }
    } else {
        // weights fp32 -> f16 into Wh = [q|k|v|p]
        int l = p - 512;  // 0..255
        int m = l >> 6;
        const float* src = (m == 0) ? Wq : (m == 1) ? Wk : (m == 2) ? Wv : Wp;
        int off = ((l & 63) * 256 + t) * 4;
        float4 vv = *(const float4*)&src[off];
        st8h(Wh + (size_t)m * NC * NC + off, pk2(vv.x, vv.y), pk2(vv.z, vv.w));
    }

    grid_barrier(bar, 768);

    // QKV: 1536 tiles, exactly 2 per block
    qkv_tile(p, xT, Wh, bq, bk, bv, Qt, Kt, Vv);
    qkv_tile(p + 768, xT, Wh, bq, bk, bv, Qt, Kt, Vv);
}

// ================= Kernel B: attention -> barrier -> proj + residual + LN =================
struct AttnS {
    half_t Pl[4][2][2][16][40];  // [wave][qt][buf][i][j]
    float  Oz[4][32][33];        // [wave][d][i]
    float  Dz[4][32];            // [wave][i]
};
struct ProjS {
    float tile[16][273];
    float ps[16][16], ps2[16][16];
    float mu[16], rs[16];
};
union SmemB { AttnS a; ProjS pj; };

__device__ __forceinline__ void attn_unit(int v, AttnS& sm,
    const half_t* __restrict__ Qt, const half_t* __restrict__ Kt,
    const half_t* __restrict__ Vv, half_t* __restrict__ At)
{
    int wv = threadIdx.x >> 6, lane = threadIdx.x & 63;
    int mm = lane & 15, q = lane >> 4;
    int bh = v & 63, iblk = v >> 6;
    int b = bh >> 3, h = bh & 7;
    int i0 = iblk * 32;

    const half_t* Qb = Qt + (size_t)bh * NHW * HD;
    const half_t* Kb = Kt + (size_t)bh * NHW * HD;
    const half_t* Vb = Vv + (size_t)bh * HD * NHW;

    half8 qf0 = *(const half8*)&Qb[(size_t)(i0 + mm) * HD + q * 8];
    half8 qf1 = *(const half8*)&Qb[(size_t)(i0 + 16 + mm) * HD + q * 8];

    const int jb = wv * 256;  // this wave's key quarter
    floatx4 zero = (floatx4){0.f, 0.f, 0.f, 0.f};
    floatx4 oa00 = zero, oa01 = zero, oa10 = zero, oa11 = zero;
    float d0 = 0.f, d1 = 0.f;
    const _Float16 z = (_Float16)0.f;
    half8 pf_p0 = {z, z, z, z, z, z, z, z}, pf_p1 = pf_p0;

    half8 kc0 = *(const half8*)&Kb[(size_t)(jb + mm) * HD + q * 8];
    half8 kc1 = *(const half8*)&Kb[(size_t)(jb + 16 + mm) * HD + q * 8];
    half8 kn0 = *(const half8*)&Kb[(size_t)(jb + 32 + mm) * HD + q * 8];
    half8 kn1 = *(const half8*)&Kb[(size_t)(jb + 48 + mm) * HD + q * 8];
    half8 vc0 = *(const half8*)&Vb[(size_t)mm * NHW + jb + q * 8];
    half8 vc1 = *(const half8*)&Vb[(size_t)(16 + mm) * NHW + jb + q * 8];
    half8 vp0 = vc0, vp1 = vc1;

    #pragma unroll 2
    for (int it = 0; it < 8; it++) {
        floatx4 s00 = __builtin_amdgcn_mfma_f32_16x16x32_f16(kc0, qf0, zero, 0, 0, 0);
        floatx4 s01 = __builtin_amdgcn_mfma_f32_16x16x32_f16(kc1, qf0, zero, 0, 0, 0);
        floatx4 s10 = __builtin_amdgcn_mfma_f32_16x16x32_f16(kc0, qf1, zero, 0, 0, 0);
        floatx4 s11 = __builtin_amdgcn_mfma_f32_16x16x32_f16(kc1, qf1, zero, 0, 0, 0);

        int jk = jb + ((it + 2) & 7) * 32;
        int jv = jb + ((it + 1) & 7) * 32;
        half8 kf0 = *(const half8*)&Kb[(size_t)(jk + mm) * HD + q * 8];
        half8 kf1 = *(const half8*)&Kb[(size_t)(jk + 16 + mm) * HD + q * 8];
        half8 vn0 = *(const half8*)&Vb[(size_t)mm * NHW + jv + q * 8];
        half8 vn1 = *(const half8*)&Vb[(size_t)(16 + mm) * NHW + jv + q * 8];

        // PV for iteration it-1 (P read issued last iteration; V retained)
        oa00 = __builtin_amdgcn_mfma_f32_16x16x32_f16(vp0, pf_p0, oa00, 0, 0, 0);
        oa01 = __builtin_amdgcn_mfma_f32_16x16x32_f16(vp1, pf_p0, oa01, 0, 0, 0);
        oa10 = __builtin_amdgcn_mfma_f32_16x16x32_f16(vp0, pf_p1, oa10, 0, 0, 0);
        oa11 = __builtin_amdgcn_mfma_f32_16x16x32_f16(vp1, pf_p1, oa11, 0, 0, 0);

        int buf = it & 1;
        {
            float e0 = EXP2(s00[0]), e1 = EXP2(s00[1]);
            float e2 = EXP2(s00[2]), e3 = EXP2(s00[3]);
            float f0 = EXP2(s01[0]), f1 = EXP2(s01[1]);
            float f2 = EXP2(s01[2]), f3 = EXP2(s01[3]);
            d0 += ((e0 + e1) + (e2 + e3)) + ((f0 + f1) + (f2 + f3));
            half_t (*PB)[40] = sm.Pl[wv][0][buf];
            st8h(&PB[mm][q * 4],      pk2(e0, e1), pk2(e2, e3));
            st8h(&PB[mm][16 + q * 4], pk2(f0, f1), pk2(f2, f3));
        }
        {
            float e0 = EXP2(s10[0]), e1 = EXP2(s10[1]);
            float e2 = EXP2(s10[2]), e3 = EXP2(s10[3]);
            float f0 = EXP2(s11[0]), f1 = EXP2(s11[1]);
            float f2 = EXP2(s11[2]), f3 = EXP2(s11[3]);
            d1 += ((e0 + e1) + (e2 + e3)) + ((f0 + f1) + (f2 + f3));
            half_t (*PB)[40] = sm.Pl[wv][1][buf];
            st8h(&PB[mm][q * 4],      pk2(e0, e1), pk2(e2, e3));
            st8h(&PB[mm][16 + q * 4], pk2(f0, f1), pk2(f2, f3));
        }
        half8 pc0 = *(const half8*)&sm.Pl[wv][0][buf][mm][q * 8];
        half8 pc1 = *(const half8*)&sm.Pl[wv][1][buf][mm][q * 8];

        kc0 = kn0; kc1 = kn1; kn0 = kf0; kn1 = kf1;
        vp0 = vc0; vp1 = vc1; vc0 = vn0; vc1 = vn1;
        pf_p0 = pc0; pf_p1 = pc1;
    }
    oa00 = __builtin_amdgcn_mfma_f32_16x16x32_f16(vp0, pf_p0, oa00, 0, 0, 0);
    oa01 = __builtin_amdgcn_mfma_f32_16x16x32_f16(vp1, pf_p0, oa01, 0, 0, 0);
    oa10 = __builtin_amdgcn_mfma_f32_16x16x32_f16(vp0, pf_p1, oa10, 0, 0, 0);
    oa11 = __builtin_amdgcn_mfma_f32_16x16x32_f16(vp1, pf_p1, oa11, 0, 0, 0);

    d0 += __shfl_xor(d0, 16); d0 += __shfl_xor(d0, 32);
    d1 += __shfl_xor(d1, 16); d1 += __shfl_xor(d1, 32);

    #pragma unroll
    for (int r = 0; r < 4; r++) {
        sm.Oz[wv][q * 4 + r][mm]           = oa00[r];
        sm.Oz[wv][16 + q * 4 + r][mm]      = oa01[r];
        sm.Oz[wv][q * 4 + r][16 + mm]      = oa10[r];
        sm.Oz[wv][16 + q * 4 + r][16 + mm] = oa11[r];
    }
    if (q == 0) { sm.Dz[wv][mm] = d0; sm.Dz[wv][16 + mm] = d1; }
    __syncthreads();

    int t = threadIdx.x;
    int iloc = t >> 3, dg = t & 7;
    float den = (sm.Dz[0][iloc] + sm.Dz[1][iloc]) + (sm.Dz[2][iloc] + sm.Dz[3][iloc]);
    float rinv = 1.f / den;
    float vo[4];
    #pragma unroll
    for (int r = 0; r < 4; r++) {
        int d = dg * 4 + r;
        vo[r] = ((sm.Oz[0][d][iloc] + sm.Oz[1][d][iloc]) +
                 (sm.Oz[2][d][iloc] + sm.Oz[3][d][iloc])) * rinv;
    }
    half_t* dst = At + ((size_t)b * NHW + i0 + iloc) * NC + h * HD + dg * 4;
    st8h(dst, pk2(vo[0], vo[1]), pk2(vo[2], vo[3]));
    __syncthreads();  // protect Oz/Dz reuse by next unit
}

__device__ __forceinline__ void projln_unit(int v, ProjS& sm,
    const half_t* __restrict__ At, const half_t* __restrict__ Wh,
    const float* __restrict__ bp, const float* __restrict__ x,
    const float* __restrict__ gamma, const float* __restrict__ beta,
    float* __restrict__ outp)
{
    int t = threadIdx.x, wv = t >> 6, lane = t & 63;
    int mm = lane & 15, q = lane >> 4;
    int b = v >> 6, s0 = (v & 63) * 16;
    const half_t* ab  = At + (size_t)b * NHW * NC;
    const half_t* Wpp = Wh + (size_t)3 * NC * NC;
    int o0 = wv * 64;

    floatx4 acc[4];
    #pragma unroll
    for (int mt = 0; mt < 4; mt++) acc[mt] = (floatx4){0.f, 0.f, 0.f, 0.f};

    #pragma unroll
    for (int k0 = 0; k0 < NC; k0 += 32) {
        half8 bf = *(const half8*)&ab[(size_t)(s0 + mm) * NC + k0 + q * 8];
        #pragma unroll
        for (int mt = 0; mt < 4; mt++) {
            half8 af = *(const half8*)&Wpp[(size_t)(o0 + mt * 16 + mm) * NC + k0 + q * 8];
            acc[mt] = __builtin_amdgcn_mfma_f32_16x16x32_f16(af, bf, acc[mt], 0, 0, 0);
        }
    }
    #pragma unroll
    for (int mt = 0; mt < 4; mt++) {
        #pragma unroll
        for (int r = 0; r < 4; r++) {
            int o = o0 + mt * 16 + q * 4 + r;
            sm.tile[mm][o] = acc[mt][r] + bp[o] + x[((size_t)b * NC + o) * NHW + s0 + mm];
        }
    }
    __syncthreads();

    int sL = t & 15, part = t >> 4;  // 16 parts x 16 channels
    float sum = 0.f, sq = 0.f;
    #pragma unroll
    for (int cc = 0; cc < 16; cc++) {
        float vv = sm.tile[sL][part * 16 + cc];
        sum += vv; sq += vv * vv;
    }
    sm.ps[part][sL] = sum; sm.ps2[part][sL] = sq;
    __syncthreads();
    if (t < 16) {
        float S = 0.f, S2 = 0.f;
        #pragma unroll
        for (int p2 = 0; p2 < 16; p2++) { S += sm.ps[p2][t]; S2 += sm.ps2[p2][t]; }
        float muv = S * (1.f / NC);
        float var = S2 * (1.f / NC) - muv * muv;
        sm.mu[t] = muv;
        sm.rs[t] = rsqrtf(var + 1e-5f);
    }
    __syncthreads();
    float muv = sm.mu[sL], rsv = sm.rs[sL];
    float* ob = outp + (size_t)b * NC * NHW;
    #pragma unroll
    for (int cc = 0; cc < 16; cc++) {
        int c = part * 16 + cc;
        ob[(size_t)c * NHW + s0 + sL] = (sm.tile[sL][c] - muv) * rsv * gamma[c] + beta[c];
    }
    __syncthreads();  // protect tile reuse by next unit
}

__global__ __launch_bounds__(256, 4) void mega_b(
    const half_t* __restrict__ Qt, const half_t* __restrict__ Kt,
    const half_t* __restrict__ Vv, half_t* __restrict__ At,
    const half_t* __restrict__ Wh, const float* __restrict__ bp,
    const float* __restrict__ x, const float* __restrict__ gamma,
    const float* __restrict__ beta, float* __restrict__ outp, unsigned* bar)
{
    __shared__ SmemB sm;
    int p = blockIdx.x;

    // attention: 2048 virtual tiles; 768 & 1536 are 0 mod 64 -> same bh per block
    attn_unit(p, sm.a, Qt, Kt, Vv, At);
    attn_unit(p + 768, sm.a, Qt, Kt, Vv, At);
    if (p < 512) attn_unit(p + 1536, sm.a, Qt, Kt, Vv, At);

    grid_barrier(bar, 768);

    // proj+LN: 512 virtual tiles on blocks 512..767 (2 each — the 2-unit attn blocks)
    if (p >= 512) {
        projln_unit((p - 512) * 2,     sm.pj, At, Wh, bp, x, gamma, beta, outp);
        projln_unit((p - 512) * 2 + 1, sm.pj, At, Wh, bp, x, gamma, beta, outp);
    }
}

extern "C" void kernel_launch(void* const* d_in, const int* in_sizes, int n_in,
                              void* d_out, int out_size, void* d_ws, size_t ws_size,
                              hipStream_t stream)
{
    const float* x     = (const float*)d_in[0];
    const float* Wq    = (const float*)d_in[1];
    const float* bq    = (const float*)d_in[2];
    const float* Wk    = (const float*)d_in[3];
    const float* bk    = (const float*)d_in[4];
    const float* Wv    = (const float*)d_in[5];
    const float* bv    = (const float*)d_in[6];
    const float* Wp    = (const float*)d_in[7];
    const float* bp    = (const float*)d_in[8];
    const float* gamma = (const float*)d_in[9];
    const float* beta  = (const float*)d_in[10];
    float* out = (float*)d_out;

    char* w = (char*)d_ws;
    half_t* xT = (half_t*)(w);                       // 4 MB f16 [b][s][c]
    half_t* Qt = (half_t*)(w + ((size_t)4  << 20));  // 4 MB [bh][s][d]
    half_t* Kt = (half_t*)(w + ((size_t)8  << 20));  // 4 MB [bh][s][d]
    half_t* Vv = (half_t*)(w + ((size_t)12 << 20));  // 4 MB [bh][d][s]
    half_t* At = (half_t*)(w + ((size_t)16 << 20));  // 4 MB [b][s][c]
    half_t* Wh = (half_t*)(w + ((size_t)20 << 20));  // 512 KB f16 [q|k|v|p]
    unsigned* bar = (unsigned*)(w + ((size_t)24 << 20));  // 2x16 barrier counters

    hipMemsetAsync(bar, 0, 128, stream);
    mega_a<<<768, 256, 0, stream>>>(Wq, Wk, Wv, Wp, x, bq, bk, bv,
                                    Wh, xT, Qt, Kt, Vv, bar);
    mega_b<<<768, 256, 0, stream>>>(Qt, Kt, Vv, At, Wh, bp, x, gamma, beta, out,
                                    bar + 16);
}

// Round 7
// 169.895 us; speedup vs baseline: 2.2830x; 2.2830x over previous
//
#include <hip/hip_runtime.h>
#include <math.h>

#define NB 8
#define NC 256
#define NHW 1024
#define NHEADS 8
#define HD 32

typedef _Float16 half_t;
typedef __attribute__((ext_vector_type(8))) _Float16 half8;
typedef __attribute__((ext_vector_type(2))) _Float16 half2v;
typedef __attribute__((ext_vector_type(4))) float floatx4;

#define EXP2(x) exp2f(x)  // v_exp_f32 IS exp2 on gfx950; log2e folded into Q scale

__device__ __forceinline__ half2v pk2(float a, float b) {
    union {
        __fp16 __attribute__((ext_vector_type(2))) r;
        half2v h;
    } u;
    u.r = __builtin_amdgcn_cvt_pkrtz(a, b);  // v_cvt_pkrtz_f16_f32
    return u.h;
}
__device__ __forceinline__ void st8h(half_t* p, half2v a, half2v b) {
    union { half2v h[2]; uint2 u; } t;
    t.h[0] = a; t.h[1] = b;
    *(uint2*)p = t.u;  // 8B store, p must be 8B-aligned
}

// ---------------- fused weight prep + x transpose ----------------
// blocks 0..255: Wq/Wk/Wv/Wp fp32 -> f16. blocks 256..767: x -> xT [b][s][c] f16
__global__ __launch_bounds__(256) void prepx(
    const float* __restrict__ Wq, const float* __restrict__ Wk,
    const float* __restrict__ Wv, const float* __restrict__ Wp,
    const float* __restrict__ x, half_t* __restrict__ Wh, half_t* __restrict__ xT)
{
    __shared__ half_t tile[64][66];
    int l = blockIdx.x;
    if (l < 256) {
        int m = l >> 6;
        const float* src = (m == 0) ? Wq : (m == 1) ? Wk : (m == 2) ? Wv : Wp;
        int off = ((l & 63) * 256 + threadIdx.x) * 4;
        float4 v = *(const float4*)&src[off];
        st8h(Wh + (size_t)m * NC * NC + off, pk2(v.x, v.y), pk2(v.z, v.w));
        return;
    }
    l -= 256;
    int t = threadIdx.x;
    int b = l >> 6;
    int i0 = ((l >> 4) & 3) * 64, s0 = (l & 15) * 64;
    const float* xb = x + ((size_t)b * NC + i0) * NHW + s0;
    int s4 = t & 15, il = t >> 4;
    #pragma unroll
    for (int r = 0; r < 4; r++) {
        int i = il + 16 * r;
        float4 v = *(const float4*)&xb[i * NHW + s4 * 4];
        *(half2v*)&tile[i][s4 * 4]     = pk2(v.x, v.y);
        *(half2v*)&tile[i][s4 * 4 + 2] = pk2(v.z, v.w);
    }
    __syncthreads();
    int iv = t & 7, sl = t >> 3;
    half_t* ob = xT + ((size_t)b * NHW + s0) * NC + i0 + iv * 8;
    #pragma unroll
    for (int r = 0; r < 2; r++) {
        int s = sl + 32 * r;
        union { half_t h[8]; int4 v4; } pkd;
        #pragma unroll
        for (int u = 0; u < 8; u++) pkd.h[u] = tile[iv * 8 + u][s];
        *(int4*)&ob[(size_t)s * NC] = pkd.v4;
    }
}

// ---------------- QKV projections via f16 MFMA ----------------
// grid (16, 4, 24). Q -> Qt[bh][s][d] scaled by (1/sqrt(32))*log2(e);
// K -> Kt[bh][s][d]; V -> Vv[bh][d][s]
__global__ __launch_bounds__(256) void qkv_mfma(
    const half_t* __restrict__ xT, const half_t* __restrict__ Wh,
    const float* __restrict__ bq, const float* __restrict__ bk, const float* __restrict__ bv,
    half_t* __restrict__ Qt, half_t* __restrict__ Kt, half_t* __restrict__ Vv)
{
    int bz = blockIdx.z;
    int b = bz & 7, p = bz >> 3;  // wave-uniform
    const half_t* W    = Wh + (size_t)p * NC * NC;
    const float*  bias = (p == 0) ? bq : (p == 1) ? bk : bv;

    int wv = threadIdx.x >> 6, lane = threadIdx.x & 63;
    int mm = lane & 15, q = lane >> 4;
    int o0 = blockIdx.y * 64 + wv * 16;
    int s0 = blockIdx.x * 64;

    const half_t* xb = xT + (size_t)b * NHW * NC;
    floatx4 acc[4];
    #pragma unroll
    for (int nt = 0; nt < 4; nt++) acc[nt] = (floatx4){0.f, 0.f, 0.f, 0.f};

    #pragma unroll
    for (int k0 = 0; k0 < NC; k0 += 32) {
        half8 af = *(const half8*)&W[(size_t)(o0 + mm) * NC + k0 + q * 8];
        #pragma unroll
        for (int nt = 0; nt < 4; nt++) {
            half8 bf = *(const half8*)&xb[(size_t)(s0 + nt * 16 + mm) * NC + k0 + q * 8];
            acc[nt] = __builtin_amdgcn_mfma_f32_16x16x32_f16(af, bf, acc[nt], 0, 0, 0);
        }
    }

    int h  = o0 >> 5;
    int bh = b * NHEADS + h;
    int d0 = (o0 & 31) + q * 4;
    float bb[4];
    #pragma unroll
    for (int r = 0; r < 4; r++) bb[r] = bias[o0 + q * 4 + r];
    // 1/sqrt(32) * log2(e): softmax via raw exp2
    const float qs = 0.17677669529663687f * 1.4426950408889634f;

    #pragma unroll
    for (int nt = 0; nt < 4; nt++) {
        int s = s0 + nt * 16 + mm;
        float v0 = acc[nt][0] + bb[0], v1 = acc[nt][1] + bb[1];
        float v2 = acc[nt][2] + bb[2], v3 = acc[nt][3] + bb[3];
        if (p == 0) { v0 *= qs; v1 *= qs; v2 *= qs; v3 *= qs; }
        if (p < 2) {
            half_t* out = (p == 0 ? Qt : Kt) + ((size_t)bh * NHW + s) * HD + d0;
            st8h(out, pk2(v0, v1), pk2(v2, v3));
        } else {
            Vv[((size_t)bh * HD + d0 + 0) * NHW + s] = (half_t)v0;
            Vv[((size_t)bh * HD + d0 + 1) * NHW + s] = (half_t)v1;
            Vv[((size_t)bh * HD + d0 + 2) * NHW + s] = (half_t)v2;
            Vv[((size_t)bh * HD + d0 + 3) * NHW + s] = (half_t)v3;
        }
    }
}

// ---------------- fused attention: 16 queries/block, j-split 4 waves ----------------
// grid 4096: bh = L&63 (XCD-local per bh), iblk = L>>6 (16 queries).
// Wave w owns keys [w*256, w*256+256), 8 iters of 32. PV lags QK one iter.
// LDS 19.7 KB -> 8 blocks/CU by LDS; launch_bounds(256,6) -> 6 blocks = 24 waves/CU.
__global__ __launch_bounds__(256, 6) void attn_mfma(
    const half_t* __restrict__ Qt, const half_t* __restrict__ Kt,
    const half_t* __restrict__ Vv, half_t* __restrict__ At)
{
    __shared__ half_t Pl[4][2][16][40];  // [wave][buf][i][j] 10.2 KB
    __shared__ float  Oz[4][32][18];     // [wave][d][i] 9.2 KB (stride 18: 2-way free)
    __shared__ float  Dz[4][16];         // [wave][i]

    int wv = threadIdx.x >> 6, lane = threadIdx.x & 63;
    int mm = lane & 15, q = lane >> 4;
    int L = blockIdx.x;
    int bh = L & 63, iblk = L >> 6;
    int b = bh >> 3, h = bh & 7;
    int i0 = iblk * 16;

    const half_t* Qb = Qt + (size_t)bh * NHW * HD;
    const half_t* Kb = Kt + (size_t)bh * NHW * HD;
    const half_t* Vb = Vv + (size_t)bh * HD * NHW;

    // Q B-fragment: B[k=d][n=i], one 16B load reused for all keys
    half8 qf = *(const half8*)&Qb[(size_t)(i0 + mm) * HD + q * 8];

    const int jb = wv * 256;  // this wave's key quarter
    floatx4 zero = (floatx4){0.f, 0.f, 0.f, 0.f};
    floatx4 oa0 = zero, oa1 = zero;
    float dacc = 0.f;
    const _Float16 z = (_Float16)0.f;
    half8 pf_p = {z, z, z, z, z, z, z, z};

    // current K/V chunk (j = jb..jb+31); vp = V of previous iter (for lagged PV)
    half8 kc0 = *(const half8*)&Kb[(size_t)(jb + mm) * HD + q * 8];
    half8 kc1 = *(const half8*)&Kb[(size_t)(jb + 16 + mm) * HD + q * 8];
    half8 vc0 = *(const half8*)&Vb[(size_t)mm * NHW + jb + q * 8];
    half8 vc1 = *(const half8*)&Vb[(size_t)(16 + mm) * NHW + jb + q * 8];
    half8 vp0 = vc0, vp1 = vc1;

    #pragma unroll
    for (int it = 0; it < 8; it++) {
        // prefetch next chunk (wrap on last iter; wrapped values unused)
        int jn = jb + ((it + 1) & 7) * 32;
        half8 kf0 = *(const half8*)&Kb[(size_t)(jn + mm) * HD + q * 8];
        half8 kf1 = *(const half8*)&Kb[(size_t)(jn + 16 + mm) * HD + q * 8];
        half8 vn0 = *(const half8*)&Vb[(size_t)mm * NHW + jn + q * 8];
        half8 vn1 = *(const half8*)&Vb[(size_t)(16 + mm) * NHW + jn + q * 8];

        // S^T: D[m=j_local][n=i]; lane (q,mm): j = 4q+r (s0) / 16+4q+r (s1), i = mm
        floatx4 s0 = __builtin_amdgcn_mfma_f32_16x16x32_f16(kc0, qf, zero, 0, 0, 0);
        floatx4 s1 = __builtin_amdgcn_mfma_f32_16x16x32_f16(kc1, qf, zero, 0, 0, 0);

        // PV for iteration it-1 (P read issued last iteration; V retained in vp)
        oa0 = __builtin_amdgcn_mfma_f32_16x16x32_f16(vp0, pf_p, oa0, 0, 0, 0);
        oa1 = __builtin_amdgcn_mfma_f32_16x16x32_f16(vp1, pf_p, oa1, 0, 0, 0);

        float e0 = EXP2(s0[0]), e1 = EXP2(s0[1]), e2 = EXP2(s0[2]), e3 = EXP2(s0[3]);
        float f0 = EXP2(s1[0]), f1 = EXP2(s1[1]), f2 = EXP2(s1[2]), f3 = EXP2(s1[3]);
        dacc += ((e0 + e1) + (e2 + e3)) + ((f0 + f1) + (f2 + f3));

        int buf = it & 1;
        half_t (*PB)[40] = Pl[wv][buf];
        st8h(&PB[mm][q * 4],      pk2(e0, e1), pk2(e2, e3));
        st8h(&PB[mm][16 + q * 4], pk2(f0, f1), pk2(f2, f3));

        // P^T B-fragment readback: B[k=j][n=i] = PB[i=mm][q*8..q*8+7]
        half8 pc = *(const half8*)&PB[mm][q * 8];

        kc0 = kf0; kc1 = kf1;
        vp0 = vc0; vp1 = vc1; vc0 = vn0; vc1 = vn1;
        pf_p = pc;
    }
    // drain PV for last iteration
    oa0 = __builtin_amdgcn_mfma_f32_16x16x32_f16(vp0, pf_p, oa0, 0, 0, 0);
    oa1 = __builtin_amdgcn_mfma_f32_16x16x32_f16(vp1, pf_p, oa1, 0, 0, 0);

    // per-wave denom for query i=mm (sum over q-groups)
    dacc += __shfl_xor(dacc, 16);
    dacc += __shfl_xor(dacc, 32);

    #pragma unroll
    for (int r = 0; r < 4; r++) {
        Oz[wv][q * 4 + r][mm]      = oa0[r];
        Oz[wv][16 + q * 4 + r][mm] = oa1[r];
    }
    if (q == 0) Dz[wv][mm] = dacc;
    __syncthreads();

    // combine 4 j-quarters, store At[b][i][h*32+d]
    int t = threadIdx.x;
    if (t < 128) {
        int iloc = t >> 3, dg = t & 7;
        float den = (Dz[0][iloc] + Dz[1][iloc]) + (Dz[2][iloc] + Dz[3][iloc]);
        float rinv = 1.f / den;
        float vo[4];
        #pragma unroll
        for (int r = 0; r < 4; r++) {
            int d = dg * 4 + r;
            vo[r] = ((Oz[0][d][iloc] + Oz[1][d][iloc]) +
                     (Oz[2][d][iloc] + Oz[3][d][iloc])) * rinv;
        }
        half_t* dst = At + ((size_t)b * NHW + i0 + iloc) * NC + h * HD + dg * 4;
        st8h(dst, pk2(vo[0], vo[1]), pk2(vo[2], vo[3]));
    }
}

// ---------------- fused output projection + residual + LayerNorm ----------------
// grid (64, 8), 512 thr / 8 waves. Wave w: o-range (w&3)*64, k-half (w>>2)*128.
__global__ __launch_bounds__(512) void projln(
    const half_t* __restrict__ At, const half_t* __restrict__ Wh,
    const float* __restrict__ bp, const float* __restrict__ x,
    const float* __restrict__ gamma, const float* __restrict__ beta,
    float* __restrict__ outp)
{
    __shared__ float tile[16][273];   // [s][c]
    __shared__ float xs[256][17];     // coalesced-staged residual [c][s]
    __shared__ float Pz[4][64][17];   // upper-k-half partials [o-wave][o_loc][s]
    __shared__ float ps[32][16], ps2[32][16];
    __shared__ float mu_s[16], rs_s[16];

    int t = threadIdx.x, wv = t >> 6, lane = t & 63;
    int mm = lane & 15, q = lane >> 4;
    int oh = wv & 3, kh = wv >> 2;
    int o0 = oh * 64;
    int b = blockIdx.y, s0 = blockIdx.x * 16;
    const half_t* ab  = At + (size_t)b * NHW * NC;
    const half_t* Wpp = Wh + (size_t)3 * NC * NC;

    // stage x coalesced: 512 thr cover 32 c x 16 s per pass
    {
        int sL = t & 15, cb = t >> 4;
        #pragma unroll
        for (int pass = 0; pass < 8; pass++) {
            int c = pass * 32 + cb;
            xs[c][sL] = x[((size_t)b * NC + c) * NHW + s0 + sL];
        }
    }

    floatx4 acc[4];
    #pragma unroll
    for (int mt = 0; mt < 4; mt++) acc[mt] = (floatx4){0.f, 0.f, 0.f, 0.f};

    int kbase = kh * 128;
    #pragma unroll
    for (int kk = 0; kk < 128; kk += 32) {
        int k0 = kbase + kk;
        half8 bf = *(const half8*)&ab[(size_t)(s0 + mm) * NC + k0 + q * 8];
        #pragma unroll
        for (int mt = 0; mt < 4; mt++) {
            half8 af = *(const half8*)&Wpp[(size_t)(o0 + mt * 16 + mm) * NC + k0 + q * 8];
            acc[mt] = __builtin_amdgcn_mfma_f32_16x16x32_f16(af, bf, acc[mt], 0, 0, 0);
        }
    }

    if (kh == 1) {
        #pragma unroll
        for (int mt = 0; mt < 4; mt++)
            #pragma unroll
            for (int r = 0; r < 4; r++)
                Pz[oh][mt * 16 + q * 4 + r][mm] = acc[mt][r];
    }
    __syncthreads();
    if (kh == 0) {
        #pragma unroll
        for (int mt = 0; mt < 4; mt++) {
            #pragma unroll
            for (int r = 0; r < 4; r++) {
                int ol = mt * 16 + q * 4 + r;
                int o = o0 + ol;
                tile[mm][o] = acc[mt][r] + Pz[oh][ol][mm] + bp[o] + xs[o][mm];
            }
        }
    }
    __syncthreads();

    // LayerNorm stats: 512 thr = 32 parts x 16 s, 8 channels each
    int sL = t & 15, part = t >> 4;
    float sum = 0.f, sq = 0.f;
    #pragma unroll
    for (int cc = 0; cc < 8; cc++) {
        float v = tile[sL][part * 8 + cc];
        sum += v; sq += v * v;
    }
    ps[part][sL] = sum; ps2[part][sL] = sq;
    __syncthreads();
    if (t < 16) {
        float S = 0.f, S2 = 0.f;
        #pragma unroll
        for (int p2 = 0; p2 < 32; p2++) { S += ps[p2][t]; S2 += ps2[p2][t]; }
        float mu  = S * (1.f / NC);
        float var = S2 * (1.f / NC) - mu * mu;
        mu_s[t] = mu;
        rs_s[t] = rsqrtf(var + 1e-5f);
    }
    __syncthreads();
    float mu = mu_s[sL], rs = rs_s[sL];
    float* ob = outp + (size_t)b * NC * NHW;
    #pragma unroll
    for (int cc = 0; cc < 8; cc++) {
        int c = part * 8 + cc;
        ob[(size_t)c * NHW + s0 + sL] = (tile[sL][c] - mu) * rs * gamma[c] + beta[c];
    }
}

extern "C" void kernel_launch(void* const* d_in, const int* in_sizes, int n_in,
                              void* d_out, int out_size, void* d_ws, size_t ws_size,
                              hipStream_t stream)
{
    const float* x     = (const float*)d_in[0];
    const float* Wq    = (const float*)d_in[1];
    const float* bq    = (const float*)d_in[2];
    const float* Wk    = (const float*)d_in[3];
    const float* bk    = (const float*)d_in[4];
    const float* Wv    = (const float*)d_in[5];
    const float* bv    = (const float*)d_in[6];
    const float* Wp    = (const float*)d_in[7];
    const float* bp    = (const float*)d_in[8];
    const float* gamma = (const float*)d_in[9];
    const float* beta  = (const float*)d_in[10];
    float* out = (float*)d_out;

    char* w = (char*)d_ws;
    half_t* xT = (half_t*)(w);                       // 4 MB f16 [b][s][c]
    half_t* Qt = (half_t*)(w + ((size_t)4  << 20));  // 4 MB [bh][s][d]
    half_t* Kt = (half_t*)(w + ((size_t)8  << 20));  // 4 MB [bh][s][d]
    half_t* Vv = (half_t*)(w + ((size_t)12 << 20));  // 4 MB [bh][d][s]
    half_t* At = (half_t*)(w + ((size_t)16 << 20));  // 4 MB [b][s][c]
    half_t* Wh = (half_t*)(w + ((size_t)20 << 20));  // 512 KB f16 [q|k|v|p]

    prepx<<<dim3(768), 256, 0, stream>>>(Wq, Wk, Wv, Wp, x, Wh, xT);
    qkv_mfma<<<dim3(16, 4, 24), 256, 0, stream>>>(xT, Wh, bq, bk, bv, Qt, Kt, Vv);
    attn_mfma<<<dim3(4096), 256, 0, stream>>>(Qt, Kt, Vv, At);
    projln<<<dim3(64, 8), 512, 0, stream>>>(At, Wh, bp, x, gamma, beta, out);
}

// Round 8
// 141.553 us; speedup vs baseline: 2.7401x; 1.2002x over previous
//
#include <hip/hip_runtime.h>
#include <math.h>

#define NB 8
#define NC 256
#define NHW 1024
#define NHEADS 8
#define HD 32

typedef _Float16 half_t;
typedef __attribute__((ext_vector_type(8))) _Float16 half8;
typedef __attribute__((ext_vector_type(4))) _Float16 half4v;
typedef __attribute__((ext_vector_type(2))) _Float16 half2v;
typedef __attribute__((ext_vector_type(4))) float floatx4;

__device__ __forceinline__ half2v pk2(float a, float b) {
    union {
        __fp16 __attribute__((ext_vector_type(2))) r;
        half2v h;
    } u;
    u.r = __builtin_amdgcn_cvt_pkrtz(a, b);  // v_cvt_pkrtz_f16_f32
    return u.h;
}
__device__ __forceinline__ void st8h(half_t* p, half2v a, half2v b) {
    union { half2v h[2]; uint2 u; } t;
    t.h[0] = a; t.h[1] = b;
    *(uint2*)p = t.u;  // 8B store, p must be 8B-aligned
}

// ---------------- fused weight prep + x transpose ----------------
// blocks 0..255: Wq/Wk/Wv/Wp fp32 -> f16. blocks 256..767: x -> xT [b][s][c] f16
__global__ __launch_bounds__(256) void prepx(
    const float* __restrict__ Wq, const float* __restrict__ Wk,
    const float* __restrict__ Wv, const float* __restrict__ Wp,
    const float* __restrict__ x, half_t* __restrict__ Wh, half_t* __restrict__ xT)
{
    __shared__ half_t tile[64][66];
    int l = blockIdx.x;
    if (l < 256) {
        int m = l >> 6;
        const float* src = (m == 0) ? Wq : (m == 1) ? Wk : (m == 2) ? Wv : Wp;
        int off = ((l & 63) * 256 + threadIdx.x) * 4;
        float4 v = *(const float4*)&src[off];
        st8h(Wh + (size_t)m * NC * NC + off, pk2(v.x, v.y), pk2(v.z, v.w));
        return;
    }
    l -= 256;
    int t = threadIdx.x;
    int b = l >> 6;
    int i0 = ((l >> 4) & 3) * 64, s0 = (l & 15) * 64;
    const float* xb = x + ((size_t)b * NC + i0) * NHW + s0;
    int s4 = t & 15, il = t >> 4;
    #pragma unroll
    for (int r = 0; r < 4; r++) {
        int i = il + 16 * r;
        float4 v = *(const float4*)&xb[i * NHW + s4 * 4];
        *(half2v*)&tile[i][s4 * 4]     = pk2(v.x, v.y);
        *(half2v*)&tile[i][s4 * 4 + 2] = pk2(v.z, v.w);
    }
    __syncthreads();
    int iv = t & 7, sl = t >> 3;
    half_t* ob = xT + ((size_t)b * NHW + s0) * NC + i0 + iv * 8;
    #pragma unroll
    for (int r = 0; r < 2; r++) {
        int s = sl + 32 * r;
        union { half_t h[8]; int4 v4; } pkd;
        #pragma unroll
        for (int u = 0; u < 8; u++) pkd.h[u] = tile[iv * 8 + u][s];
        *(int4*)&ob[(size_t)s * NC] = pkd.v4;
    }
}

// ---------------- QKV projections: register-blocked f16 MFMA ----------------
// grid (16, 2, 24), 256 thr. Wave = 32o x 64s (2 A-frags x 4 B-frags -> 8 MFMA/k-step).
// Wave wv covers o in [by*128 + wv*32, +32) -> exactly one head: h = by*4 + wv.
// Q -> Qt[bh][s][d] scaled by (1/sqrt(32))*log2(e); K -> Kt[bh][s][d]; V -> Vv[bh][d][s]
__global__ __launch_bounds__(256) void qkv_mfma(
    const half_t* __restrict__ xT, const half_t* __restrict__ Wh,
    const float* __restrict__ bq, const float* __restrict__ bk, const float* __restrict__ bv,
    half_t* __restrict__ Qt, half_t* __restrict__ Kt, half_t* __restrict__ Vv)
{
    int bz = blockIdx.z;
    int b = bz & 7, p = bz >> 3;  // wave-uniform
    const half_t* W    = Wh + (size_t)p * NC * NC;
    const float*  bias = (p == 0) ? bq : (p == 1) ? bk : bv;

    int wv = threadIdx.x >> 6, lane = threadIdx.x & 63;
    int mm = lane & 15, q = lane >> 4;
    int o0 = blockIdx.y * 128 + wv * 32;
    int s0 = blockIdx.x * 64;

    const half_t* xb = xT + (size_t)b * NHW * NC;
    floatx4 acc[2][4];
    #pragma unroll
    for (int mt = 0; mt < 2; mt++)
        #pragma unroll
        for (int nt = 0; nt < 4; nt++) acc[mt][nt] = (floatx4){0.f, 0.f, 0.f, 0.f};

    #pragma unroll
    for (int k0 = 0; k0 < NC; k0 += 32) {
        half8 af[2], bf[4];
        #pragma unroll
        for (int mt = 0; mt < 2; mt++)
            af[mt] = *(const half8*)&W[(size_t)(o0 + mt * 16 + mm) * NC + k0 + q * 8];
        #pragma unroll
        for (int nt = 0; nt < 4; nt++)
            bf[nt] = *(const half8*)&xb[(size_t)(s0 + nt * 16 + mm) * NC + k0 + q * 8];
        #pragma unroll
        for (int mt = 0; mt < 2; mt++)
            #pragma unroll
            for (int nt = 0; nt < 4; nt++)
                acc[mt][nt] = __builtin_amdgcn_mfma_f32_16x16x32_f16(af[mt], bf[nt], acc[mt][nt], 0, 0, 0);
    }

    int h  = (o0 >> 5);              // = blockIdx.y*4 + wv
    int bh = b * NHEADS + h;
    // 1/sqrt(32) * log2(e): softmax via raw exp2 in attn
    const float qs = 0.17677669529663687f * 1.4426950408889634f;

    #pragma unroll
    for (int mt = 0; mt < 2; mt++) {
        int d0 = mt * 16 + q * 4;    // d within head, 0..31
        float bb[4];
        #pragma unroll
        for (int r = 0; r < 4; r++) bb[r] = bias[o0 + mt * 16 + q * 4 + r];
        #pragma unroll
        for (int nt = 0; nt < 4; nt++) {
            int s = s0 + nt * 16 + mm;
            float v0 = acc[mt][nt][0] + bb[0], v1 = acc[mt][nt][1] + bb[1];
            float v2 = acc[mt][nt][2] + bb[2], v3 = acc[mt][nt][3] + bb[3];
            if (p == 0) { v0 *= qs; v1 *= qs; v2 *= qs; v3 *= qs; }
            if (p < 2) {
                half_t* out = (p == 0 ? Qt : Kt) + ((size_t)bh * NHW + s) * HD + d0;
                st8h(out, pk2(v0, v1), pk2(v2, v3));
            } else {
                Vv[((size_t)bh * HD + d0 + 0) * NHW + s] = (half_t)v0;
                Vv[((size_t)bh * HD + d0 + 1) * NHW + s] = (half_t)v1;
                Vv[((size_t)bh * HD + d0 + 2) * NHW + s] = (half_t)v2;
                Vv[((size_t)bh * HD + d0 + 3) * NHW + s] = (half_t)v3;
            }
        }
    }
}

// ---------------- fused attention: S^T, j-split across waves, XCD swizzle ----------------
// grid 2048 linear: bh = L&63 (same-bh blocks share an XCD), iblk = L>>6 (32 queries).
// Block = 32 queries x 1024 keys; wave w owns keys [w*256, w*256+256), 8 iters of 32.
// PV lags QK by one iteration. P tile stride 36 halfs (R2-measured conflict-free),
// read back as two 8B LDS reads (8B-aligned at stride 72B).
__global__ __launch_bounds__(256) void attn_mfma(
    const half_t* __restrict__ Qt, const half_t* __restrict__ Kt,
    const half_t* __restrict__ Vv, half_t* __restrict__ At)
{
    __shared__ half_t Pl[4][2][2][16][36];  // [wave][qt][buf][i][j]
    __shared__ float Oz[4][32][34];         // [wave][d][i] stride 34: 2-way max
    __shared__ float Dz[4][32];             // [wave][i]

    int wv = threadIdx.x >> 6, lane = threadIdx.x & 63;
    int mm = lane & 15, q = lane >> 4;
    int L = blockIdx.x;
    int bh = L & 63, iblk = L >> 6;
    int b = bh >> 3, h = bh & 7;
    int i0 = iblk * 32;

    const half_t* Qb = Qt + (size_t)bh * NHW * HD;
    const half_t* Kb = Kt + (size_t)bh * NHW * HD;
    const half_t* Vb = Vv + (size_t)bh * HD * NHW;

    half8 qf0 = *(const half8*)&Qb[(size_t)(i0 + mm) * HD + q * 8];
    half8 qf1 = *(const half8*)&Qb[(size_t)(i0 + 16 + mm) * HD + q * 8];

    const int jb = wv * 256;  // this wave's key quarter
    floatx4 zero = (floatx4){0.f, 0.f, 0.f, 0.f};
    floatx4 oa00 = zero, oa01 = zero, oa10 = zero, oa11 = zero;
    float d0 = 0.f, d1 = 0.f;
    const _Float16 z = (_Float16)0.f;
    half8 pf_p0 = {z, z, z, z, z, z, z, z}, pf_p1 = pf_p0;

    half8 kc0 = *(const half8*)&Kb[(size_t)(jb + mm) * HD + q * 8];
    half8 kc1 = *(const half8*)&Kb[(size_t)(jb + 16 + mm) * HD + q * 8];
    half8 kn0 = *(const half8*)&Kb[(size_t)(jb + 32 + mm) * HD + q * 8];
    half8 kn1 = *(const half8*)&Kb[(size_t)(jb + 48 + mm) * HD + q * 8];
    half8 vc0 = *(const half8*)&Vb[(size_t)mm * NHW + jb + q * 8];
    half8 vc1 = *(const half8*)&Vb[(size_t)(16 + mm) * NHW + jb + q * 8];
    half8 vp0 = vc0, vp1 = vc1;

    #pragma unroll
    for (int it = 0; it < 8; it++) {
        floatx4 s00 = __builtin_amdgcn_mfma_f32_16x16x32_f16(kc0, qf0, zero, 0, 0, 0);
        floatx4 s01 = __builtin_amdgcn_mfma_f32_16x16x32_f16(kc1, qf0, zero, 0, 0, 0);
        floatx4 s10 = __builtin_amdgcn_mfma_f32_16x16x32_f16(kc0, qf1, zero, 0, 0, 0);
        floatx4 s11 = __builtin_amdgcn_mfma_f32_16x16x32_f16(kc1, qf1, zero, 0, 0, 0);

        int jk = jb + ((it + 2) & 7) * 32;
        int jv = jb + ((it + 1) & 7) * 32;
        half8 kf0 = *(const half8*)&Kb[(size_t)(jk + mm) * HD + q * 8];
        half8 kf1 = *(const half8*)&Kb[(size_t)(jk + 16 + mm) * HD + q * 8];
        half8 vn0 = *(const half8*)&Vb[(size_t)mm * NHW + jv + q * 8];
        half8 vn1 = *(const half8*)&Vb[(size_t)(16 + mm) * NHW + jv + q * 8];

        // PV for iteration it-1 (P read issued last iteration; V retained)
        oa00 = __builtin_amdgcn_mfma_f32_16x16x32_f16(vp0, pf_p0, oa00, 0, 0, 0);
        oa01 = __builtin_amdgcn_mfma_f32_16x16x32_f16(vp1, pf_p0, oa01, 0, 0, 0);
        oa10 = __builtin_amdgcn_mfma_f32_16x16x32_f16(vp0, pf_p1, oa10, 0, 0, 0);
        oa11 = __builtin_amdgcn_mfma_f32_16x16x32_f16(vp1, pf_p1, oa11, 0, 0, 0);

        int buf = it & 1;
        {
            float e0 = exp2f(s00[0]), e1 = exp2f(s00[1]);
            float e2 = exp2f(s00[2]), e3 = exp2f(s00[3]);
            float f0 = exp2f(s01[0]), f1 = exp2f(s01[1]);
            float f2 = exp2f(s01[2]), f3 = exp2f(s01[3]);
            d0 += ((e0 + e1) + (e2 + e3)) + ((f0 + f1) + (f2 + f3));
            half_t (*PB)[36] = Pl[wv][0][buf];
            st8h(&PB[mm][q * 4],      pk2(e0, e1), pk2(e2, e3));
            st8h(&PB[mm][16 + q * 4], pk2(f0, f1), pk2(f2, f3));
        }
        {
            float e0 = exp2f(s10[0]), e1 = exp2f(s10[1]);
            float e2 = exp2f(s10[2]), e3 = exp2f(s10[3]);
            float f0 = exp2f(s11[0]), f1 = exp2f(s11[1]);
            float f2 = exp2f(s11[2]), f3 = exp2f(s11[3]);
            d1 += ((e0 + e1) + (e2 + e3)) + ((f0 + f1) + (f2 + f3));
            half_t (*PB)[36] = Pl[wv][1][buf];
            st8h(&PB[mm][q * 4],      pk2(e0, e1), pk2(e2, e3));
            st8h(&PB[mm][16 + q * 4], pk2(f0, f1), pk2(f2, f3));
        }
        // read back P^T B-fragments as two 8B reads (stride 72B is 8B-aligned)
        union { half4v h4[2]; half8 h8; } u0, u1;
        u0.h4[0] = *(half4v*)&Pl[wv][0][buf][mm][q * 8];
        u0.h4[1] = *(half4v*)&Pl[wv][0][buf][mm][q * 8 + 4];
        u1.h4[0] = *(half4v*)&Pl[wv][1][buf][mm][q * 8];
        u1.h4[1] = *(half4v*)&Pl[wv][1][buf][mm][q * 8 + 4];

        kc0 = kn0; kc1 = kn1; kn0 = kf0; kn1 = kf1;
        vp0 = vc0; vp1 = vc1; vc0 = vn0; vc1 = vn1;
        pf_p0 = u0.h8; pf_p1 = u1.h8;
    }
    oa00 = __builtin_amdgcn_mfma_f32_16x16x32_f16(vp0, pf_p0, oa00, 0, 0, 0);
    oa01 = __builtin_amdgcn_mfma_f32_16x16x32_f16(vp1, pf_p0, oa01, 0, 0, 0);
    oa10 = __builtin_amdgcn_mfma_f32_16x16x32_f16(vp0, pf_p1, oa10, 0, 0, 0);
    oa11 = __builtin_amdgcn_mfma_f32_16x16x32_f16(vp1, pf_p1, oa11, 0, 0, 0);

    d0 += __shfl_xor(d0, 16); d0 += __shfl_xor(d0, 32);
    d1 += __shfl_xor(d1, 16); d1 += __shfl_xor(d1, 32);

    #pragma unroll
    for (int r = 0; r < 4; r++) {
        Oz[wv][q * 4 + r][mm]           = oa00[r];
        Oz[wv][16 + q * 4 + r][mm]      = oa01[r];
        Oz[wv][q * 4 + r][16 + mm]      = oa10[r];
        Oz[wv][16 + q * 4 + r][16 + mm] = oa11[r];
    }
    if (q == 0) { Dz[wv][mm] = d0; Dz[wv][16 + mm] = d1; }
    __syncthreads();

    // combine 4 j-quarters and store At[b][i][h*32+d]
    int t = threadIdx.x;
    int iloc = t >> 3, dg = t & 7;
    float den = (Dz[0][iloc] + Dz[1][iloc]) + (Dz[2][iloc] + Dz[3][iloc]);
    float rinv = 1.f / den;
    float v[4];
    #pragma unroll
    for (int r = 0; r < 4; r++) {
        int d = dg * 4 + r;
        v[r] = ((Oz[0][d][iloc] + Oz[1][d][iloc]) + (Oz[2][d][iloc] + Oz[3][d][iloc])) * rinv;
    }
    half_t* dst = At + ((size_t)b * NHW + i0 + iloc) * NC + h * HD + dg * 4;
    st8h(dst, pk2(v[0], v[1]), pk2(v[2], v[3]));
}

// ---------------- fused output projection + residual + LayerNorm ----------------
// grid (64, 8), 512 thr / 8 waves. Wave w: o-range (w&3)*64, k-half (w>>2)*128.
__global__ __launch_bounds__(512) void projln(
    const half_t* __restrict__ At, const half_t* __restrict__ Wh,
    const float* __restrict__ bp, const float* __restrict__ x,
    const float* __restrict__ gamma, const float* __restrict__ beta,
    float* __restrict__ outp)
{
    __shared__ float tile[16][273];   // [s][c]
    __shared__ float xs[256][17];     // coalesced-staged residual [c][s]
    __shared__ float Pz[4][64][17];   // upper-k-half partials [o-wave][o_loc][s]
    __shared__ float ps[32][16], ps2[32][16];
    __shared__ float mu_s[16], rs_s[16];

    int t = threadIdx.x, wv = t >> 6, lane = t & 63;
    int mm = lane & 15, q = lane >> 4;
    int oh = wv & 3, kh = wv >> 2;
    int o0 = oh * 64;
    int b = blockIdx.y, s0 = blockIdx.x * 16;
    const half_t* ab  = At + (size_t)b * NHW * NC;
    const half_t* Wpp = Wh + (size_t)3 * NC * NC;

    {
        int sL = t & 15, cb = t >> 4;
        #pragma unroll
        for (int pass = 0; pass < 8; pass++) {
            int c = pass * 32 + cb;
            xs[c][sL] = x[((size_t)b * NC + c) * NHW + s0 + sL];
        }
    }

    floatx4 acc[4];
    #pragma unroll
    for (int mt = 0; mt < 4; mt++) acc[mt] = (floatx4){0.f, 0.f, 0.f, 0.f};

    int kbase = kh * 128;
    #pragma unroll
    for (int kk = 0; kk < 128; kk += 32) {
        int k0 = kbase + kk;
        half8 bf = *(const half8*)&ab[(size_t)(s0 + mm) * NC + k0 + q * 8];
        #pragma unroll
        for (int mt = 0; mt < 4; mt++) {
            half8 af = *(const half8*)&Wpp[(size_t)(o0 + mt * 16 + mm) * NC + k0 + q * 8];
            acc[mt] = __builtin_amdgcn_mfma_f32_16x16x32_f16(af, bf, acc[mt], 0, 0, 0);
        }
    }

    if (kh == 1) {
        #pragma unroll
        for (int mt = 0; mt < 4; mt++)
            #pragma unroll
            for (int r = 0; r < 4; r++)
                Pz[oh][mt * 16 + q * 4 + r][mm] = acc[mt][r];
    }
    __syncthreads();
    if (kh == 0) {
        #pragma unroll
        for (int mt = 0; mt < 4; mt++) {
            #pragma unroll
            for (int r = 0; r < 4; r++) {
                int ol = mt * 16 + q * 4 + r;
                int o = o0 + ol;
                tile[mm][o] = acc[mt][r] + Pz[oh][ol][mm] + bp[o] + xs[o][mm];
            }
        }
    }
    __syncthreads();

    int sL = t & 15, part = t >> 4;
    float sum = 0.f, sq = 0.f;
    #pragma unroll
    for (int cc = 0; cc < 8; cc++) {
        float v = tile[sL][part * 8 + cc];
        sum += v; sq += v * v;
    }
    ps[part][sL] = sum; ps2[part][sL] = sq;
    __syncthreads();
    if (t < 16) {
        float S = 0.f, S2 = 0.f;
        #pragma unroll
        for (int p2 = 0; p2 < 32; p2++) { S += ps[p2][t]; S2 += ps2[p2][t]; }
        float mu  = S * (1.f / NC);
        float var = S2 * (1.f / NC) - mu * mu;
        mu_s[t] = mu;
        rs_s[t] = rsqrtf(var + 1e-5f);
    }
    __syncthreads();
    float mu = mu_s[sL], rs = rs_s[sL];
    float* ob = outp + (size_t)b * NC * NHW;
    #pragma unroll
    for (int cc = 0; cc < 8; cc++) {
        int c = part * 8 + cc;
        ob[(size_t)c * NHW + s0 + sL] = (tile[sL][c] - mu) * rs * gamma[c] + beta[c];
    }
}

extern "C" void kernel_launch(void* const* d_in, const int* in_sizes, int n_in,
                              void* d_out, int out_size, void* d_ws, size_t ws_size,
                              hipStream_t stream)
{
    const float* x     = (const float*)d_in[0];
    const float* Wq    = (const float*)d_in[1];
    const float* bq    = (const float*)d_in[2];
    const float* Wk    = (const float*)d_in[3];
    const float* bk    = (const float*)d_in[4];
    const float* Wv    = (const float*)d_in[5];
    const float* bv    = (const float*)d_in[6];
    const float* Wp    = (const float*)d_in[7];
    const float* bp    = (const float*)d_in[8];
    const float* gamma = (const float*)d_in[9];
    const float* beta  = (const float*)d_in[10];
    float* out = (float*)d_out;

    char* w = (char*)d_ws;
    half_t* xT = (half_t*)(w);                       // 4 MB f16 [b][s][c]
    half_t* Qt = (half_t*)(w + ((size_t)4  << 20));  // 4 MB [bh][s][d]
    half_t* Kt = (half_t*)(w + ((size_t)8  << 20));  // 4 MB [bh][s][d]
    half_t* Vv = (half_t*)(w + ((size_t)12 << 20));  // 4 MB [bh][d][s]
    half_t* At = (half_t*)(w + ((size_t)16 << 20));  // 4 MB [b][s][c]
    half_t* Wh = (half_t*)(w + ((size_t)20 << 20));  // 512 KB f16 [q|k|v|p]

    prepx<<<dim3(768), 256, 0, stream>>>(Wq, Wk, Wv, Wp, x, Wh, xT);
    qkv_mfma<<<dim3(16, 2, 24), 256, 0, stream>>>(xT, Wh, bq, bk, bv, Qt, Kt, Vv);
    attn_mfma<<<dim3(2048), 256, 0, stream>>>(Qt, Kt, Vv, At);
    projln<<<dim3(64, 8), 512, 0, stream>>>(At, Wh, bp, x, gamma, beta, out);
}

// Round 9
// 140.121 us; speedup vs baseline: 2.7681x; 1.0102x over previous
//
#include <hip/hip_runtime.h>
#include <math.h>

#define NB 8
#define NC 256
#define NHW 1024
#define NHEADS 8
#define HD 32

typedef _Float16 half_t;
typedef __attribute__((ext_vector_type(8))) _Float16 half8;
typedef __attribute__((ext_vector_type(4))) _Float16 half4v;
typedef __attribute__((ext_vector_type(2))) _Float16 half2v;
typedef __attribute__((ext_vector_type(4))) float floatx4;

__device__ __forceinline__ half2v pk2(float a, float b) {
    union {
        __fp16 __attribute__((ext_vector_type(2))) r;
        half2v h;
    } u;
    u.r = __builtin_amdgcn_cvt_pkrtz(a, b);  // v_cvt_pkrtz_f16_f32
    return u.h;
}
__device__ __forceinline__ void st8h(half_t* p, half2v a, half2v b) {
    union { half2v h[2]; uint2 u; } t;
    t.h[0] = a; t.h[1] = b;
    *(uint2*)p = t.u;  // 8B store, p must be 8B-aligned
}
// fp32 row (k-contiguous) -> f16 A-fragment
__device__ __forceinline__ half8 ldw8(const float* p) {
    float4 w0 = *(const float4*)p;
    float4 w1 = *(const float4*)(p + 4);
    union { half2v h2[4]; half8 h8; } u;
    u.h2[0] = pk2(w0.x, w0.y); u.h2[1] = pk2(w0.z, w0.w);
    u.h2[2] = pk2(w1.x, w1.y); u.h2[3] = pk2(w1.z, w1.w);
    return u.h8;
}

// ---------------- QKV: fused x-transpose (LDS) + register-blocked f16 MFMA ----------------
// grid (16, 2, 24), 256 thr. bz = b + 8*p. Block stages x[b][all c][s0..s0+63] -> LDS
// transposed f16 [s][c], then wave = 32o x 64s (2 A x 4 B frags -> 8 MFMA/k-step).
// Q -> Qt[bh][s][d] scaled by (1/sqrt(32))*log2(e); K -> Kt[bh][s][d]; V -> Vv[bh][d][s]
__global__ __launch_bounds__(256) void qkv_mfma(
    const float* __restrict__ x,
    const float* __restrict__ Wq, const float* __restrict__ Wk, const float* __restrict__ Wv,
    const float* __restrict__ bq, const float* __restrict__ bk, const float* __restrict__ bv,
    half_t* __restrict__ Qt, half_t* __restrict__ Kt, half_t* __restrict__ Vv)
{
    __shared__ half_t xs[64][264];  // [s][c], stride 264: b32 writes 2-way, b128 reads 2-way

    int bz = blockIdx.z;
    int b = bz & 7, p = bz >> 3;  // wave-uniform
    const float* W    = (p == 0) ? Wq : (p == 1) ? Wk : Wv;
    const float* bias = (p == 0) ? bq : (p == 1) ? bk : bv;

    int t = threadIdx.x;
    int s0 = blockIdx.x * 64;
    const float* xb = x + (size_t)b * NC * NHW;

    // stage + transpose + convert: pairs of c rows -> half2 LDS writes
    {
        int sf = t & 15, cp = t >> 4;  // sf: s-group (4 floats), cp: c-pair 0..15
        #pragma unroll
        for (int pass = 0; pass < 8; pass++) {
            int c = cp * 2 + 32 * pass;
            float4 a  = *(const float4*)&xb[(size_t)c * NHW + s0 + sf * 4];
            float4 bb = *(const float4*)&xb[(size_t)(c + 1) * NHW + s0 + sf * 4];
            *(half2v*)&xs[sf * 4 + 0][c] = pk2(a.x, bb.x);
            *(half2v*)&xs[sf * 4 + 1][c] = pk2(a.y, bb.y);
            *(half2v*)&xs[sf * 4 + 2][c] = pk2(a.z, bb.z);
            *(half2v*)&xs[sf * 4 + 3][c] = pk2(a.w, bb.w);
        }
    }
    __syncthreads();

    int wv = t >> 6, lane = t & 63;
    int mm = lane & 15, q = lane >> 4;
    int o0 = blockIdx.y * 128 + wv * 32;

    floatx4 acc[2][4];
    #pragma unroll
    for (int mt = 0; mt < 2; mt++)
        #pragma unroll
        for (int nt = 0; nt < 4; nt++) acc[mt][nt] = (floatx4){0.f, 0.f, 0.f, 0.f};

    #pragma unroll
    for (int k0 = 0; k0 < NC; k0 += 32) {
        half8 af[2], bf[4];
        #pragma unroll
        for (int mt = 0; mt < 2; mt++)
            af[mt] = ldw8(&W[(size_t)(o0 + mt * 16 + mm) * NC + k0 + q * 8]);
        #pragma unroll
        for (int nt = 0; nt < 4; nt++)
            bf[nt] = *(const half8*)&xs[nt * 16 + mm][k0 + q * 8];
        #pragma unroll
        for (int mt = 0; mt < 2; mt++)
            #pragma unroll
            for (int nt = 0; nt < 4; nt++)
                acc[mt][nt] = __builtin_amdgcn_mfma_f32_16x16x32_f16(af[mt], bf[nt], acc[mt][nt], 0, 0, 0);
    }

    int h  = (o0 >> 5);  // = blockIdx.y*4 + wv
    int bh = b * NHEADS + h;
    // 1/sqrt(32) * log2(e): softmax via raw exp2 in attn
    const float qs = 0.17677669529663687f * 1.4426950408889634f;

    #pragma unroll
    for (int mt = 0; mt < 2; mt++) {
        int d0 = mt * 16 + q * 4;  // d within head
        float bb[4];
        #pragma unroll
        for (int r = 0; r < 4; r++) bb[r] = bias[o0 + mt * 16 + q * 4 + r];
        #pragma unroll
        for (int nt = 0; nt < 4; nt++) {
            int s = s0 + nt * 16 + mm;
            float v0 = acc[mt][nt][0] + bb[0], v1 = acc[mt][nt][1] + bb[1];
            float v2 = acc[mt][nt][2] + bb[2], v3 = acc[mt][nt][3] + bb[3];
            if (p == 0) { v0 *= qs; v1 *= qs; v2 *= qs; v3 *= qs; }
            if (p < 2) {
                half_t* out = (p == 0 ? Qt : Kt) + ((size_t)bh * NHW + s) * HD + d0;
                st8h(out, pk2(v0, v1), pk2(v2, v3));
            } else {
                Vv[((size_t)bh * HD + d0 + 0) * NHW + s] = (half_t)v0;
                Vv[((size_t)bh * HD + d0 + 1) * NHW + s] = (half_t)v1;
                Vv[((size_t)bh * HD + d0 + 2) * NHW + s] = (half_t)v2;
                Vv[((size_t)bh * HD + d0 + 3) * NHW + s] = (half_t)v3;
            }
        }
    }
}

// ---------------- fused attention: S^T, j-split across waves, XCD swizzle ----------------
// (unchanged from R8 — best measured) grid 2048: bh = L&63, iblk = L>>6 (32 queries).
__global__ __launch_bounds__(256) void attn_mfma(
    const half_t* __restrict__ Qt, const half_t* __restrict__ Kt,
    const half_t* __restrict__ Vv, half_t* __restrict__ At)
{
    __shared__ half_t Pl[4][2][2][16][36];  // [wave][qt][buf][i][j]
    __shared__ float Oz[4][32][34];         // [wave][d][i] stride 34: 2-way max
    __shared__ float Dz[4][32];             // [wave][i]

    int wv = threadIdx.x >> 6, lane = threadIdx.x & 63;
    int mm = lane & 15, q = lane >> 4;
    int L = blockIdx.x;
    int bh = L & 63, iblk = L >> 6;
    int b = bh >> 3, h = bh & 7;
    int i0 = iblk * 32;

    const half_t* Qb = Qt + (size_t)bh * NHW * HD;
    const half_t* Kb = Kt + (size_t)bh * NHW * HD;
    const half_t* Vb = Vv + (size_t)bh * HD * NHW;

    half8 qf0 = *(const half8*)&Qb[(size_t)(i0 + mm) * HD + q * 8];
    half8 qf1 = *(const half8*)&Qb[(size_t)(i0 + 16 + mm) * HD + q * 8];

    const int jb = wv * 256;  // this wave's key quarter
    floatx4 zero = (floatx4){0.f, 0.f, 0.f, 0.f};
    floatx4 oa00 = zero, oa01 = zero, oa10 = zero, oa11 = zero;
    float d0 = 0.f, d1 = 0.f;
    const _Float16 z = (_Float16)0.f;
    half8 pf_p0 = {z, z, z, z, z, z, z, z}, pf_p1 = pf_p0;

    half8 kc0 = *(const half8*)&Kb[(size_t)(jb + mm) * HD + q * 8];
    half8 kc1 = *(const half8*)&Kb[(size_t)(jb + 16 + mm) * HD + q * 8];
    half8 kn0 = *(const half8*)&Kb[(size_t)(jb + 32 + mm) * HD + q * 8];
    half8 kn1 = *(const half8*)&Kb[(size_t)(jb + 48 + mm) * HD + q * 8];
    half8 vc0 = *(const half8*)&Vb[(size_t)mm * NHW + jb + q * 8];
    half8 vc1 = *(const half8*)&Vb[(size_t)(16 + mm) * NHW + jb + q * 8];
    half8 vp0 = vc0, vp1 = vc1;

    #pragma unroll
    for (int it = 0; it < 8; it++) {
        floatx4 s00 = __builtin_amdgcn_mfma_f32_16x16x32_f16(kc0, qf0, zero, 0, 0, 0);
        floatx4 s01 = __builtin_amdgcn_mfma_f32_16x16x32_f16(kc1, qf0, zero, 0, 0, 0);
        floatx4 s10 = __builtin_amdgcn_mfma_f32_16x16x32_f16(kc0, qf1, zero, 0, 0, 0);
        floatx4 s11 = __builtin_amdgcn_mfma_f32_16x16x32_f16(kc1, qf1, zero, 0, 0, 0);

        int jk = jb + ((it + 2) & 7) * 32;
        int jv = jb + ((it + 1) & 7) * 32;
        half8 kf0 = *(const half8*)&Kb[(size_t)(jk + mm) * HD + q * 8];
        half8 kf1 = *(const half8*)&Kb[(size_t)(jk + 16 + mm) * HD + q * 8];
        half8 vn0 = *(const half8*)&Vb[(size_t)mm * NHW + jv + q * 8];
        half8 vn1 = *(const half8*)&Vb[(size_t)(16 + mm) * NHW + jv + q * 8];

        // PV for iteration it-1 (P read issued last iteration; V retained)
        oa00 = __builtin_amdgcn_mfma_f32_16x16x32_f16(vp0, pf_p0, oa00, 0, 0, 0);
        oa01 = __builtin_amdgcn_mfma_f32_16x16x32_f16(vp1, pf_p0, oa01, 0, 0, 0);
        oa10 = __builtin_amdgcn_mfma_f32_16x16x32_f16(vp0, pf_p1, oa10, 0, 0, 0);
        oa11 = __builtin_amdgcn_mfma_f32_16x16x32_f16(vp1, pf_p1, oa11, 0, 0, 0);

        int buf = it & 1;
        {
            float e0 = exp2f(s00[0]), e1 = exp2f(s00[1]);
            float e2 = exp2f(s00[2]), e3 = exp2f(s00[3]);
            float f0 = exp2f(s01[0]), f1 = exp2f(s01[1]);
            float f2 = exp2f(s01[2]), f3 = exp2f(s01[3]);
            d0 += ((e0 + e1) + (e2 + e3)) + ((f0 + f1) + (f2 + f3));
            half_t (*PB)[36] = Pl[wv][0][buf];
            st8h(&PB[mm][q * 4],      pk2(e0, e1), pk2(e2, e3));
            st8h(&PB[mm][16 + q * 4], pk2(f0, f1), pk2(f2, f3));
        }
        {
            float e0 = exp2f(s10[0]), e1 = exp2f(s10[1]);
            float e2 = exp2f(s10[2]), e3 = exp2f(s10[3]);
            float f0 = exp2f(s11[0]), f1 = exp2f(s11[1]);
            float f2 = exp2f(s11[2]), f3 = exp2f(s11[3]);
            d1 += ((e0 + e1) + (e2 + e3)) + ((f0 + f1) + (f2 + f3));
            half_t (*PB)[36] = Pl[wv][1][buf];
            st8h(&PB[mm][q * 4],      pk2(e0, e1), pk2(e2, e3));
            st8h(&PB[mm][16 + q * 4], pk2(f0, f1), pk2(f2, f3));
        }
        // read back P^T B-fragments as two 8B reads (stride 72B is 8B-aligned)
        union { half4v h4[2]; half8 h8; } u0, u1;
        u0.h4[0] = *(half4v*)&Pl[wv][0][buf][mm][q * 8];
        u0.h4[1] = *(half4v*)&Pl[wv][0][buf][mm][q * 8 + 4];
        u1.h4[0] = *(half4v*)&Pl[wv][1][buf][mm][q * 8];
        u1.h4[1] = *(half4v*)&Pl[wv][1][buf][mm][q * 8 + 4];

        kc0 = kn0; kc1 = kn1; kn0 = kf0; kn1 = kf1;
        vp0 = vc0; vp1 = vc1; vc0 = vn0; vc1 = vn1;
        pf_p0 = u0.h8; pf_p1 = u1.h8;
    }
    oa00 = __builtin_amdgcn_mfma_f32_16x16x32_f16(vp0, pf_p0, oa00, 0, 0, 0);
    oa01 = __builtin_amdgcn_mfma_f32_16x16x32_f16(vp1, pf_p0, oa01, 0, 0, 0);
    oa10 = __builtin_amdgcn_mfma_f32_16x16x32_f16(vp0, pf_p1, oa10, 0, 0, 0);
    oa11 = __builtin_amdgcn_mfma_f32_16x16x32_f16(vp1, pf_p1, oa11, 0, 0, 0);

    d0 += __shfl_xor(d0, 16); d0 += __shfl_xor(d0, 32);
    d1 += __shfl_xor(d1, 16); d1 += __shfl_xor(d1, 32);

    #pragma unroll
    for (int r = 0; r < 4; r++) {
        Oz[wv][q * 4 + r][mm]           = oa00[r];
        Oz[wv][16 + q * 4 + r][mm]      = oa01[r];
        Oz[wv][q * 4 + r][16 + mm]      = oa10[r];
        Oz[wv][16 + q * 4 + r][16 + mm] = oa11[r];
    }
    if (q == 0) { Dz[wv][mm] = d0; Dz[wv][16 + mm] = d1; }
    __syncthreads();

    int t = threadIdx.x;
    int iloc = t >> 3, dg = t & 7;
    float den = (Dz[0][iloc] + Dz[1][iloc]) + (Dz[2][iloc] + Dz[3][iloc]);
    float rinv = 1.f / den;
    float v[4];
    #pragma unroll
    for (int r = 0; r < 4; r++) {
        int d = dg * 4 + r;
        v[r] = ((Oz[0][d][iloc] + Oz[1][d][iloc]) + (Oz[2][d][iloc] + Oz[3][d][iloc])) * rinv;
    }
    half_t* dst = At + ((size_t)b * NHW + i0 + iloc) * NC + h * HD + dg * 4;
    st8h(dst, pk2(v[0], v[1]), pk2(v[2], v[3]));
}

// ---------------- fused output projection + residual + LayerNorm ----------------
// grid (64, 8), 512 thr / 8 waves. Wave w: o-range (w&3)*64, k-half (w>>2)*128.
// Wp consumed fp32 directly (inline cvt).
__global__ __launch_bounds__(512) void projln(
    const half_t* __restrict__ At, const float* __restrict__ Wp,
    const float* __restrict__ bp, const float* __restrict__ x,
    const float* __restrict__ gamma, const float* __restrict__ beta,
    float* __restrict__ outp)
{
    __shared__ float tile[16][273];   // [s][c]
    __shared__ float xs[256][17];     // coalesced-staged residual [c][s]
    __shared__ float Pz[4][64][17];   // upper-k-half partials [o-wave][o_loc][s]
    __shared__ float ps[32][16], ps2[32][16];
    __shared__ float mu_s[16], rs_s[16];

    int t = threadIdx.x, wv = t >> 6, lane = t & 63;
    int mm = lane & 15, q = lane >> 4;
    int oh = wv & 3, kh = wv >> 2;
    int o0 = oh * 64;
    int b = blockIdx.y, s0 = blockIdx.x * 16;
    const half_t* ab = At + (size_t)b * NHW * NC;

    {
        int sL = t & 15, cb = t >> 4;
        #pragma unroll
        for (int pass = 0; pass < 8; pass++) {
            int c = pass * 32 + cb;
            xs[c][sL] = x[((size_t)b * NC + c) * NHW + s0 + sL];
        }
    }

    floatx4 acc[4];
    #pragma unroll
    for (int mt = 0; mt < 4; mt++) acc[mt] = (floatx4){0.f, 0.f, 0.f, 0.f};

    int kbase = kh * 128;
    #pragma unroll
    for (int kk = 0; kk < 128; kk += 32) {
        int k0 = kbase + kk;
        half8 bf = *(const half8*)&ab[(size_t)(s0 + mm) * NC + k0 + q * 8];
        #pragma unroll
        for (int mt = 0; mt < 4; mt++) {
            half8 af = ldw8(&Wp[(size_t)(o0 + mt * 16 + mm) * NC + k0 + q * 8]);
            acc[mt] = __builtin_amdgcn_mfma_f32_16x16x32_f16(af, bf, acc[mt], 0, 0, 0);
        }
    }

    if (kh == 1) {
        #pragma unroll
        for (int mt = 0; mt < 4; mt++)
            #pragma unroll
            for (int r = 0; r < 4; r++)
                Pz[oh][mt * 16 + q * 4 + r][mm] = acc[mt][r];
    }
    __syncthreads();
    if (kh == 0) {
        #pragma unroll
        for (int mt = 0; mt < 4; mt++) {
            #pragma unroll
            for (int r = 0; r < 4; r++) {
                int ol = mt * 16 + q * 4 + r;
                int o = o0 + ol;
                tile[mm][o] = acc[mt][r] + Pz[oh][ol][mm] + bp[o] + xs[o][mm];
            }
        }
    }
    __syncthreads();

    int sL = t & 15, part = t >> 4;
    float sum = 0.f, sq = 0.f;
    #pragma unroll
    for (int cc = 0; cc < 8; cc++) {
        float v = tile[sL][part * 8 + cc];
        sum += v; sq += v * v;
    }
    ps[part][sL] = sum; ps2[part][sL] = sq;
    __syncthreads();
    if (t < 16) {
        float S = 0.f, S2 = 0.f;
        #pragma unroll
        for (int p2 = 0; p2 < 32; p2++) { S += ps[p2][t]; S2 += ps2[p2][t]; }
        float mu  = S * (1.f / NC);
        float var = S2 * (1.f / NC) - mu * mu;
        mu_s[t] = mu;
        rs_s[t] = rsqrtf(var + 1e-5f);
    }
    __syncthreads();
    float mu = mu_s[sL], rs = rs_s[sL];
    float* ob = outp + (size_t)b * NC * NHW;
    #pragma unroll
    for (int cc = 0; cc < 8; cc++) {
        int c = part * 8 + cc;
        ob[(size_t)c * NHW + s0 + sL] = (tile[sL][c] - mu) * rs * gamma[c] + beta[c];
    }
}

extern "C" void kernel_launch(void* const* d_in, const int* in_sizes, int n_in,
                              void* d_out, int out_size, void* d_ws, size_t ws_size,
                              hipStream_t stream)
{
    const float* x     = (const float*)d_in[0];
    const float* Wq    = (const float*)d_in[1];
    const float* bq    = (const float*)d_in[2];
    const float* Wk    = (const float*)d_in[3];
    const float* bk    = (const float*)d_in[4];
    const float* Wv    = (const float*)d_in[5];
    const float* bv    = (const float*)d_in[6];
    const float* Wp    = (const float*)d_in[7];
    const float* bp    = (const float*)d_in[8];
    const float* gamma = (const float*)d_in[9];
    const float* beta  = (const float*)d_in[10];
    float* out = (float*)d_out;

    char* w = (char*)d_ws;
    half_t* Qt = (half_t*)(w);                       // 4 MB [bh][s][d]
    half_t* Kt = (half_t*)(w + ((size_t)4  << 20));  // 4 MB [bh][s][d]
    half_t* Vv = (half_t*)(w + ((size_t)8  << 20));  // 4 MB [bh][d][s]
    half_t* At = (half_t*)(w + ((size_t)12 << 20));  // 4 MB [b][s][c]

    qkv_mfma<<<dim3(16, 2, 24), 256, 0, stream>>>(x, Wq, Wk, Wv, bq, bk, bv, Qt, Kt, Vv);
    attn_mfma<<<dim3(2048), 256, 0, stream>>>(Qt, Kt, Vv, At);
    projln<<<dim3(64, 8), 512, 0, stream>>>(At, Wp, bp, x, gamma, beta, out);
}